// Round 17
// baseline (60.815 us; speedup 1.0000x reference)
//
#include <hip/hip_runtime.h>
#include <hip/hip_bf16.h>

#define B_ 128
#define T_ 256
#define D_ 1024
#define L_ 48
#define SMALL_ (-1000.0f)

typedef float f32x4 __attribute__((ext_vector_type(4)));
typedef short bf16x8 __attribute__((ext_vector_type(8)));
typedef short bf16x4 __attribute__((ext_vector_type(4)));
typedef unsigned u32x4 __attribute__((ext_vector_type(4)));
typedef unsigned u32x2 __attribute__((ext_vector_type(2)));

__device__ __forceinline__ float bcastf(float v, int lane) {
    return __uint_as_float(__builtin_amdgcn_readlane(__float_as_uint(v), lane));
}
__device__ __forceinline__ unsigned cvt_pk_bf16(float lo, float hi) {
    unsigned r;
    asm("v_cvt_pk_bf16_f32 %0, %1, %2" : "=v"(r) : "v"(lo), "v"(hi));
    return r;
}
__device__ __forceinline__ bf16x4 pack4(float a, float b, float c, float d) {
    u32x2 u = {cvt_pk_bf16(a, b), cvt_pk_bf16(c, d)};
    return __builtin_bit_cast(bf16x4, u);
}
__device__ __forceinline__ f32x4 mfma16(bf16x4 a, bf16x4 b, f32x4 c) {
#if __has_builtin(__builtin_amdgcn_mfma_f32_16x16x16bf16_1k)
    return __builtin_amdgcn_mfma_f32_16x16x16bf16_1k(a, b, c, 0, 0, 0);
#else
    asm volatile("v_mfma_f32_16x16x16_bf16 %0, %1, %2, %0" : "+v"(c) : "v"(a), "v"(b));
    return c;
#endif
}
__device__ __forceinline__ unsigned short f2bfu(float f) {
    unsigned u = __float_as_uint(f);
    return (unsigned short)((u + 0x7FFFu + ((u >> 16) & 1u)) >> 16);
}

// ---------- Kernel 1: W -> bf16 fragment-sequential layout, E^T -> bf16, zero ticket ----------
__global__ __launch_bounds__(256) void prep_kernel(const float* __restrict__ W,
                                                   const float* __restrict__ trans,
                                                   unsigned short* __restrict__ wpk,
                                                   unsigned short* __restrict__ etbf,
                                                   unsigned* __restrict__ cnt) {
    int i = blockIdx.x * 256 + threadIdx.x;   // 49152 total
    if (i == 0) *cnt = 0u;
    {
        int e    = i & 7;
        int lane = (i >> 3) & 63;
        int g    = i >> 9;                    // 0..95
        int t    = g % 3;
        int kh   = (g / 3) & 1;
        int r    = g / 6;
        int row  = t * 16 + (lane & 15);
        int col  = r * 64 + kh * 32 + (lane >> 4) * 8 + e;
        wpk[i] = f2bfu(W[row * D_ + col]);
    }
    if (i < L_ * L_) {
        int r = i / L_, k = i - r * L_;       // etbf[r][k] = exp(trans[k][r])
        etbf[i] = f2bfu(__expf(trans[k * L_ + r]));
    }
}

// ---------- Kernel 2: LDS-staged GEMM (R16-proven) + gold (wave 2) + 2x 16-step chunks ----------
// Block i = (b = i>>3, c = i&7) -> rows i*32 .. i*32+31.  NO fences/atomics (R10 lesson).
__global__ __launch_bounds__(256, 4) void gemmchunk_kernel(const float* __restrict__ x,
                                                           const unsigned short* __restrict__ wpk,
                                                           const float* __restrict__ bias,
                                                           const unsigned short* __restrict__ etbf,
                                                           const float* __restrict__ trans,
                                                           const int* __restrict__ tags,
                                                           const int* __restrict__ seq_len,
                                                           float* __restrict__ Xout,
                                                           float* __restrict__ lsc,
                                                           float* __restrict__ gsc) {
    __shared__ float red[2][64][12];              // 6 KB: K-split reduction
    __shared__ float elds[32 * L_];               // 6 KB: exp(pred) tile
    __shared__ unsigned short xbl[2][32][72];     // 9 KB: bf16 x-tile, dbuf, pad->stride 144B
    const int tid = threadIdx.x;
    const int wv = tid >> 6;
    const int lane = tid & 63;
    const int pair = wv >> 1;
    const int kh = wv & 1;
    const int l16 = lane & 15;
    const int lg  = lane >> 4;
    const int b = blockIdx.x >> 3, c = blockIdx.x & 7;
    const int n = seq_len[b];

    // ---- GEMM phase (R16 byte-identical) ----
    {
        const int srow = tid >> 4;
        const int scol = (tid & 15) * 4;          // float col base
        const float* xs0 = x + ((size_t)blockIdx.x * 32 + srow) * D_ + scol;
        const float* xs1 = xs0 + 16 * (size_t)D_;
        const unsigned short* wlane = wpk + lane * 8;

        f32x4 acc0 = {0.f,0.f,0.f,0.f}, acc1 = {0.f,0.f,0.f,0.f}, acc2 = {0.f,0.f,0.f,0.f};

        {
            float4 a0 = *reinterpret_cast<const float4*>(xs0);
            float4 a1 = *reinterpret_cast<const float4*>(xs1);
            u32x2 p0 = {cvt_pk_bf16(a0.x, a0.y), cvt_pk_bf16(a0.z, a0.w)};
            u32x2 p1 = {cvt_pk_bf16(a1.x, a1.y), cvt_pk_bf16(a1.z, a1.w)};
            *reinterpret_cast<u32x2*>(&xbl[0][srow][scol]) = p0;
            *reinterpret_cast<u32x2*>(&xbl[0][16 + srow][scol]) = p1;
        }
        float4 s0[2], s1[2];
        s0[1] = *reinterpret_cast<const float4*>(xs0 + 64);
        s1[1] = *reinterpret_cast<const float4*>(xs1 + 64);

        #pragma unroll
        for (int r = 0; r < 16; ++r) {
            if (r + 2 < 16) {
                s0[r & 1] = *reinterpret_cast<const float4*>(xs0 + (r + 2) * 64);
                s1[r & 1] = *reinterpret_cast<const float4*>(xs1 + (r + 2) * 64);
            }
            __syncthreads();                       // buf[r&1] writes visible
            bf16x8 af = *reinterpret_cast<const bf16x8*>(&xbl[r & 1][pair * 16 + l16][kh * 32 + lg * 8]);
            const unsigned short* wp = wlane + ((r * 6 + kh * 3) << 9);
            bf16x8 b0 = *reinterpret_cast<const bf16x8*>(wp);
            bf16x8 b1 = *reinterpret_cast<const bf16x8*>(wp + 512);
            bf16x8 b2 = *reinterpret_cast<const bf16x8*>(wp + 1024);
            acc0 = __builtin_amdgcn_mfma_f32_16x16x32_bf16(af, b0, acc0, 0, 0, 0);
            acc1 = __builtin_amdgcn_mfma_f32_16x16x32_bf16(af, b1, acc1, 0, 0, 0);
            acc2 = __builtin_amdgcn_mfma_f32_16x16x32_bf16(af, b2, acc2, 0, 0, 0);
            if (r + 1 < 16) {
                float4 a0 = s0[(r + 1) & 1];
                float4 a1 = s1[(r + 1) & 1];
                u32x2 p0 = {cvt_pk_bf16(a0.x, a0.y), cvt_pk_bf16(a0.z, a0.w)};
                u32x2 p1 = {cvt_pk_bf16(a1.x, a1.y), cvt_pk_bf16(a1.z, a1.w)};
                *reinterpret_cast<u32x2*>(&xbl[(r + 1) & 1][srow][scol]) = p0;
                *reinterpret_cast<u32x2*>(&xbl[(r + 1) & 1][16 + srow][scol]) = p1;
            }
        }

        if (kh == 1) {
            #pragma unroll
            for (int r = 0; r < 4; ++r) {
                red[pair][lane][r]     = acc0[r];
                red[pair][lane][4 + r] = acc1[r];
                red[pair][lane][8 + r] = acc2[r];
            }
        }
        __syncthreads();
        if (kh == 0) {
            float bi0 = bias[l16], bi1 = bias[16 + l16], bi2 = bias[32 + l16];
            #pragma unroll
            for (int r = 0; r < 4; ++r) {
                float v0 = acc0[r] + red[pair][lane][r]     + bi0;
                float v1 = acc1[r] + red[pair][lane][4 + r] + bi1;
                float v2 = acc2[r] + red[pair][lane][8 + r] + bi2;
                int lrow = pair * 16 + lg * 4 + r;
                elds[lrow * L_ + l16]      = __expf(v0);
                elds[lrow * L_ + 16 + l16] = __expf(v1);
                elds[lrow * L_ + 32 + l16] = (32 + l16 >= L_ - 2) ? 0.f : __expf(v2);
            }
        }
    }
    __syncthreads();                  // elds complete
    if (wv == 3) return;              // retire one wave immediately

    if (wv == 2) {
        // ---- gold-path partial for rows [c*32, c*32+32), pred = log(elds) ----
        const int* tg = tags + b * T_;
        float s = 0.f;
        int t = c * 32 + lane;        // lanes 0..31 active
        if (lane < 32 && t < n) {
            int tag = tg[t];
            int pt = (t == 0) ? (L_ - 2) : tg[t - 1];
            s = __logf(elds[lane * L_ + tag]) + trans[pt * L_ + tag];
            if (t == n - 1) s += trans[tag * L_ + (L_ - 1)];
        }
        #pragma unroll
        for (int o = 32; o > 0; o >>= 1) s += __shfl_xor(s, o, 64);
        if (lane == 0) gsc[blockIdx.x] = s;
        return;
    }

    // ---- chunk product: waves 0 and 1 each run 16 steps (R7/R8 math) ----
    const int wvbase = wv * 16;                    // elds row base for this wave
    int nsteps = n - (c * 32 + wvbase);
    nsteps = nsteps < 0 ? 0 : (nsteps > 16 ? 16 : nsteps);

    const int l15 = lane & 15, g = lane >> 4;
    bf16x4 A[3][3];
    #pragma unroll
    for (int mt = 0; mt < 3; ++mt)
        #pragma unroll
        for (int kt = 0; kt < 3; ++kt)
            A[mt][kt] = *reinterpret_cast<const bf16x4*>(etbf + (16 * mt + l15) * L_ + 16 * kt + 4 * g);

    f32x4 Cst[3][3];
    #pragma unroll
    for (int mt = 0; mt < 3; ++mt)
        #pragma unroll
        for (int nt = 0; nt < 3; ++nt)
            #pragma unroll
            for (int r = 0; r < 4; ++r)
                Cst[mt][nt][r] = (mt == nt && 4 * g + r == l15) ? 1.f : 0.f;

    float lsum = 0.f;
    for (int q = 0; q < nsteps; ++q) {
        bf16x4 Bf[3][3];
        #pragma unroll
        for (int kt = 0; kt < 3; ++kt)
            #pragma unroll
            for (int nt = 0; nt < 3; ++nt)
                Bf[kt][nt] = pack4(Cst[kt][nt][0], Cst[kt][nt][1], Cst[kt][nt][2], Cst[kt][nt][3]);

        f32x4 C[3][3];
        #pragma unroll
        for (int mt = 0; mt < 3; ++mt)
            #pragma unroll
            for (int nt = 0; nt < 3; ++nt)
                C[mt][nt] = f32x4{0.f, 0.f, 0.f, 0.f};
        #pragma unroll
        for (int kt = 0; kt < 3; ++kt)
            #pragma unroll
            for (int mt = 0; mt < 3; ++mt)
                #pragma unroll
                for (int nt = 0; nt < 3; ++nt)
                    C[mt][nt] = mfma16(A[mt][kt], Bf[kt][nt], C[mt][nt]);

        float4 w0 = *reinterpret_cast<const float4*>(elds + (wvbase + q) * L_ + 4 * g);
        float4 w1 = *reinterpret_cast<const float4*>(elds + (wvbase + q) * L_ + 16 + 4 * g);
        float4 w2 = *reinterpret_cast<const float4*>(elds + (wvbase + q) * L_ + 32 + 4 * g);

        float rn = 1.f;
        if ((q & 3) == 3) {
            float r = bcastf(C[0][0][0], 0);
            rn = __builtin_amdgcn_rcpf(r);
            lsum += __logf(r);
        }
        float sr[12];
        sr[0] = w0.x * rn; sr[1] = w0.y * rn; sr[2]  = w0.z * rn; sr[3]  = w0.w * rn;
        sr[4] = w1.x * rn; sr[5] = w1.y * rn; sr[6]  = w1.z * rn; sr[7]  = w1.w * rn;
        sr[8] = w2.x * rn; sr[9] = w2.y * rn; sr[10] = w2.z * rn; sr[11] = w2.w * rn;
        #pragma unroll
        for (int mt = 0; mt < 3; ++mt)
            #pragma unroll
            for (int nt = 0; nt < 3; ++nt)
                #pragma unroll
                for (int r = 0; r < 4; ++r)
                    Cst[mt][nt][r] = C[mt][nt][r] * sr[4 * mt + r];
    }

    float* xo = Xout + (size_t)(blockIdx.x * 2 + wv) * 2304;
    #pragma unroll
    for (int mt = 0; mt < 3; ++mt)
        #pragma unroll
        for (int nt = 0; nt < 3; ++nt)
            #pragma unroll
            for (int r = 0; r < 4; ++r)
                xo[(16 * mt + 4 * g + r) * L_ + 16 * nt + l15] = Cst[mt][nt][r];
    if (lane == 0) lsc[blockIdx.x * 2 + wv] = lsum;
}

// ---------- Kernel 3: per-batch combine (16 matvecs) + gold sum + ticket reduce ----------
__global__ __launch_bounds__(64) void combine_kernel(const float* __restrict__ Xout,
                                                     const float* __restrict__ lsc,
                                                     const float* __restrict__ gsc,
                                                     const float* __restrict__ trans,
                                                     float* __restrict__ res,
                                                     unsigned* __restrict__ cnt,
                                                     float* __restrict__ out) {
    const int b = blockIdx.x;
    const int j = threadIdx.x;

    float sc = 0.f;
    #pragma unroll
    for (int cc = 0; cc < 8; ++cc) sc += gsc[b * 8 + cc];

    __shared__ float vbuf[64];
    float v = (j == L_ - 2) ? 1.f : 0.f;
    vbuf[j] = v;
    float lsum = 0.f;
    #pragma unroll 1
    for (int c = 0; c < 16; ++c) {
        const float* X = Xout + (size_t)(b * 16 + c) * 2304;
        lsum += lsc[b * 16 + c];
        float acc = 0.f;
        if (j < L_) {
            const float4* vb4 = reinterpret_cast<const float4*>(vbuf);
            const float4* xr = reinterpret_cast<const float4*>(X + j * L_);
            #pragma unroll
            for (int ci = 0; ci < 12; ++ci) {
                float4 xx = xr[ci];
                float4 vv = vb4[ci];
                acc = fmaf(xx.x, vv.x, acc);
                acc = fmaf(xx.y, vv.y, acc);
                acc = fmaf(xx.z, vv.z, acc);
                acc = fmaf(xx.w, vv.w, acc);
            }
        }
        float r = bcastf(acc, 0);              // alpha[0] > 0 always
        float rn = __builtin_amdgcn_rcpf(r);
        lsum += __logf(r);
        v = acc * rn;
        vbuf[j] = (j < L_) ? v : 0.f;
    }

    float term = (j < L_) ? v * __expf(trans[j * L_ + (L_ - 1)]) : 0.f;
    #pragma unroll
    for (int o = 32; o > 0; o >>= 1) term += __shfl_xor(term, o, 64);
    float logz = __logf(term) + lsum;

    if (j == 0) res[b] = logz - sc;
    __threadfence();
    unsigned old = 0;
    if (j == 0) old = atomicAdd(cnt, 1u);
    old = __builtin_amdgcn_readlane(old, 0);
    if (old == B_ - 1) {
        __threadfence();
        volatile const float* vr = res;
        float v2 = vr[j] + vr[64 + j];
        #pragma unroll
        for (int o = 32; o > 0; o >>= 1) v2 += __shfl_xor(v2, o, 64);
        if (j == 0) out[0] = v2;
    }
}

extern "C" void kernel_launch(void* const* d_in, const int* in_sizes, int n_in,
                              void* d_out, int out_size, void* d_ws, size_t ws_size,
                              hipStream_t stream) {
    const float* x      = (const float*)d_in[0];
    const float* W      = (const float*)d_in[1];
    const float* bias   = (const float*)d_in[2];
    const float* trans  = (const float*)d_in[3];
    const int*   tags   = (const int*)d_in[4];
    const int*   seqlen = (const int*)d_in[5];
    float* out = (float*)d_out;

    unsigned short* wpk  = (unsigned short*)d_ws;                          // 98304 B
    unsigned short* etbf = (unsigned short*)((char*)d_ws + 98304);         // 4608 B
    float* Xout          = (float*)((char*)d_ws + 102912);                 // 18874368 B (2048 x 2304 f32)
    float* lsc           = (float*)((char*)d_ws + 18977280);               // 8192 B
    float* gsc           = (float*)((char*)d_ws + 18985472);               // 4096 B
    float* res           = (float*)((char*)d_ws + 18989568);               // 512 B
    unsigned* cnt        = (unsigned*)((char*)d_ws + 18990080);            // 4 B

    hipLaunchKernelGGL(prep_kernel, dim3(192), dim3(256), 0, stream, W, trans, wpk, etbf, cnt);
    hipLaunchKernelGGL(gemmchunk_kernel, dim3(1024), dim3(256), 0, stream,
                       x, wpk, bias, etbf, trans, tags, seqlen, Xout, lsc, gsc);
    hipLaunchKernelGGL(combine_kernel, dim3(B_), dim3(64), 0, stream,
                       Xout, lsc, gsc, trans, res, cnt, out);
}

// Round 19
// 55.554 us; speedup vs baseline: 1.0947x; 1.0947x over previous
//
#include <hip/hip_runtime.h>
#include <hip/hip_bf16.h>

#define B_ 128
#define T_ 256
#define D_ 1024
#define L_ 48
#define SMALL_ (-1000.0f)

typedef float f32x4 __attribute__((ext_vector_type(4)));
typedef short bf16x8 __attribute__((ext_vector_type(8)));
typedef short bf16x4 __attribute__((ext_vector_type(4)));
typedef unsigned u32x4 __attribute__((ext_vector_type(4)));
typedef unsigned u32x2 __attribute__((ext_vector_type(2)));

__device__ __forceinline__ float bcastf(float v, int lane) {
    return __uint_as_float(__builtin_amdgcn_readlane(__float_as_uint(v), lane));
}
__device__ __forceinline__ unsigned cvt_pk_bf16(float lo, float hi) {
    unsigned r;
    asm("v_cvt_pk_bf16_f32 %0, %1, %2" : "=v"(r) : "v"(lo), "v"(hi));
    return r;
}
__device__ __forceinline__ bf16x4 pack4(float a, float b, float c, float d) {
    u32x2 u = {cvt_pk_bf16(a, b), cvt_pk_bf16(c, d)};
    return __builtin_bit_cast(bf16x4, u);
}
__device__ __forceinline__ f32x4 mfma16(bf16x4 a, bf16x4 b, f32x4 c) {
#if __has_builtin(__builtin_amdgcn_mfma_f32_16x16x16bf16_1k)
    return __builtin_amdgcn_mfma_f32_16x16x16bf16_1k(a, b, c, 0, 0, 0);
#else
    asm volatile("v_mfma_f32_16x16x16_bf16 %0, %1, %2, %0" : "+v"(c) : "v"(a), "v"(b));
    return c;
#endif
}
__device__ __forceinline__ unsigned short f2bfu(float f) {
    unsigned u = __float_as_uint(f);
    return (unsigned short)((u + 0x7FFFu + ((u >> 16) & 1u)) >> 16);
}

// ---------- Kernel 1: W -> bf16 fragment-sequential layout, E^T -> bf16, zero ticket ----------
__global__ __launch_bounds__(256) void prep_kernel(const float* __restrict__ W,
                                                   const float* __restrict__ trans,
                                                   unsigned short* __restrict__ wpk,
                                                   unsigned short* __restrict__ etbf,
                                                   unsigned* __restrict__ cnt) {
    int i = blockIdx.x * 256 + threadIdx.x;   // 49152 total
    if (i == 0) *cnt = 0u;
    {
        int e    = i & 7;
        int lane = (i >> 3) & 63;
        int g    = i >> 9;                    // 0..95
        int t    = g % 3;
        int kh   = (g / 3) & 1;
        int r    = g / 6;
        int row  = t * 16 + (lane & 15);
        int col  = r * 64 + kh * 32 + (lane >> 4) * 8 + e;
        wpk[i] = f2bfu(W[row * D_ + col]);
    }
    if (i < L_ * L_) {
        int r = i / L_, k = i - r * L_;       // etbf[r][k] = exp(trans[k][r])
        etbf[i] = f2bfu(__expf(trans[k * L_ + r]));
    }
}

// ---------- Kernel 2: LDS-staged GEMM (depth-3 reg prefetch) + gold partial + chunk ----------
// Block i = (b = i>>3, c = i&7) -> rows i*32 .. i*32+31.  NO fences/atomics (R10 lesson).
// LDS pipeline: R16-proven double-buffer with barrier EVERY round (frozen structure).
__global__ __launch_bounds__(256, 4) void gemmchunk_kernel(const float* __restrict__ x,
                                                           const unsigned short* __restrict__ wpk,
                                                           const float* __restrict__ bias,
                                                           const unsigned short* __restrict__ etbf,
                                                           const float* __restrict__ trans,
                                                           const int* __restrict__ tags,
                                                           const int* __restrict__ seq_len,
                                                           float* __restrict__ Xout,
                                                           float* __restrict__ lsc,
                                                           float* __restrict__ gsc) {
    __shared__ float red[2][64][12];              // 6 KB: K-split reduction
    __shared__ float elds[32 * L_];               // 6 KB: exp(pred) tile
    __shared__ unsigned short xbl[2][32][72];     // 9 KB: bf16 x-tile, dbuf, pad->stride 144B
    const int tid = threadIdx.x;
    const int wv = tid >> 6;
    const int lane = tid & 63;
    const int pair = wv >> 1;
    const int kh = wv & 1;
    const int l16 = lane & 15;
    const int lg  = lane >> 4;
    const int b = blockIdx.x >> 3, c = blockIdx.x & 7;
    const int n = seq_len[b];

    // ---- GEMM phase: staged x (contiguous loads, depth-3 reg prefetch), fragment-seq W ----
    {
        const int srow = tid >> 4;
        const int scol = (tid & 15) * 4;          // float col base
        const float* xs0 = x + ((size_t)blockIdx.x * 32 + srow) * D_ + scol;
        const float* xs1 = xs0 + 16 * (size_t)D_;
        const unsigned short* wlane = wpk + lane * 8;

        f32x4 acc0 = {0.f,0.f,0.f,0.f}, acc1 = {0.f,0.f,0.f,0.f}, acc2 = {0.f,0.f,0.f,0.f};

        // prologue: stage round 0 into buf 0 directly
        {
            float4 a0 = *reinterpret_cast<const float4*>(xs0);
            float4 a1 = *reinterpret_cast<const float4*>(xs1);
            u32x2 p0 = {cvt_pk_bf16(a0.x, a0.y), cvt_pk_bf16(a0.z, a0.w)};
            u32x2 p1 = {cvt_pk_bf16(a1.x, a1.y), cvt_pk_bf16(a1.z, a1.w)};
            *reinterpret_cast<u32x2*>(&xbl[0][srow][scol]) = p0;
            *reinterpret_cast<u32x2*>(&xbl[0][16 + srow][scol]) = p1;
        }
        // preload rounds 1,2 into slots 1,2 (slot s holds round == s mod 3)
        float4 s0[3], s1[3];
        s0[1] = *reinterpret_cast<const float4*>(xs0 + 64);
        s1[1] = *reinterpret_cast<const float4*>(xs1 + 64);
        s0[2] = *reinterpret_cast<const float4*>(xs0 + 128);
        s1[2] = *reinterpret_cast<const float4*>(xs1 + 128);

        #pragma unroll
        for (int r = 0; r < 16; ++r) {
            // issue loads for round r+3 into slot r%3 (consumed at end of round r-1)
            if (r + 3 < 16) {
                s0[r % 3] = *reinterpret_cast<const float4*>(xs0 + (r + 3) * 64);
                s1[r % 3] = *reinterpret_cast<const float4*>(xs1 + (r + 3) * 64);
            }
            __syncthreads();                       // buf[r&1] writes visible (R16 structure)
            bf16x8 af = *reinterpret_cast<const bf16x8*>(&xbl[r & 1][pair * 16 + l16][kh * 32 + lg * 8]);
            const unsigned short* wp = wlane + ((r * 6 + kh * 3) << 9);
            bf16x8 b0 = *reinterpret_cast<const bf16x8*>(wp);
            bf16x8 b1 = *reinterpret_cast<const bf16x8*>(wp + 512);
            bf16x8 b2 = *reinterpret_cast<const bf16x8*>(wp + 1024);
            acc0 = __builtin_amdgcn_mfma_f32_16x16x32_bf16(af, b0, acc0, 0, 0, 0);
            acc1 = __builtin_amdgcn_mfma_f32_16x16x32_bf16(af, b1, acc1, 0, 0, 0);
            acc2 = __builtin_amdgcn_mfma_f32_16x16x32_bf16(af, b2, acc2, 0, 0, 0);
            if (r + 1 < 16) {                      // stage round r+1 (loaded ~2.5 rounds ago)
                float4 a0 = s0[(r + 1) % 3];
                float4 a1 = s1[(r + 1) % 3];
                u32x2 p0 = {cvt_pk_bf16(a0.x, a0.y), cvt_pk_bf16(a0.z, a0.w)};
                u32x2 p1 = {cvt_pk_bf16(a1.x, a1.y), cvt_pk_bf16(a1.z, a1.w)};
                *reinterpret_cast<u32x2*>(&xbl[(r + 1) & 1][srow][scol]) = p0;
                *reinterpret_cast<u32x2*>(&xbl[(r + 1) & 1][16 + srow][scol]) = p1;
            }
        }

        if (kh == 1) {
            #pragma unroll
            for (int r = 0; r < 4; ++r) {
                red[pair][lane][r]     = acc0[r];
                red[pair][lane][4 + r] = acc1[r];
                red[pair][lane][8 + r] = acc2[r];
            }
        }
        __syncthreads();
        if (kh == 0) {
            float bi0 = bias[l16], bi1 = bias[16 + l16], bi2 = bias[32 + l16];
            #pragma unroll
            for (int r = 0; r < 4; ++r) {
                float v0 = acc0[r] + red[pair][lane][r]     + bi0;
                float v1 = acc1[r] + red[pair][lane][4 + r] + bi1;
                float v2 = acc2[r] + red[pair][lane][8 + r] + bi2;
                int lrow = pair * 16 + lg * 4 + r;
                elds[lrow * L_ + l16]      = __expf(v0);
                elds[lrow * L_ + 16 + l16] = __expf(v1);
                elds[lrow * L_ + 32 + l16] = (32 + l16 >= L_ - 2) ? 0.f : __expf(v2);
            }
        }
    }
    __syncthreads();                  // elds complete
    if (wv >= 2) return;              // R8 retirement profile

    if (wv == 1) {
        // ---- gold-path partial for rows [c*32, c*32+32), pred = log(elds) ----
        const int* tg = tags + b * T_;
        float s = 0.f;
        int t = c * 32 + lane;        // lanes 0..31 active
        if (lane < 32 && t < n) {
            int tag = tg[t];
            int pt = (t == 0) ? (L_ - 2) : tg[t - 1];
            s = __logf(elds[lane * L_ + tag]) + trans[pt * L_ + tag];
            if (t == n - 1) s += trans[tag * L_ + (L_ - 1)];
        }
        #pragma unroll
        for (int o = 32; o > 0; o >>= 1) s += __shfl_xor(s, o, 64);
        if (lane == 0) gsc[blockIdx.x] = s;
        return;
    }

    // ---- chunk product (R7/R8-proven), wave 0 only ----
    int nsteps = n - c * 32;
    nsteps = nsteps < 0 ? 0 : (nsteps > 32 ? 32 : nsteps);

    const int l15 = lane & 15, g = lane >> 4;
    bf16x4 A[3][3];
    #pragma unroll
    for (int mt = 0; mt < 3; ++mt)
        #pragma unroll
        for (int kt = 0; kt < 3; ++kt)
            A[mt][kt] = *reinterpret_cast<const bf16x4*>(etbf + (16 * mt + l15) * L_ + 16 * kt + 4 * g);

    f32x4 Cst[3][3];
    #pragma unroll
    for (int mt = 0; mt < 3; ++mt)
        #pragma unroll
        for (int nt = 0; nt < 3; ++nt)
            #pragma unroll
            for (int r = 0; r < 4; ++r)
                Cst[mt][nt][r] = (mt == nt && 4 * g + r == l15) ? 1.f : 0.f;

    float lsum = 0.f;
    for (int q = 0; q < nsteps; ++q) {
        bf16x4 Bf[3][3];
        #pragma unroll
        for (int kt = 0; kt < 3; ++kt)
            #pragma unroll
            for (int nt = 0; nt < 3; ++nt)
                Bf[kt][nt] = pack4(Cst[kt][nt][0], Cst[kt][nt][1], Cst[kt][nt][2], Cst[kt][nt][3]);

        f32x4 C[3][3];
        #pragma unroll
        for (int mt = 0; mt < 3; ++mt)
            #pragma unroll
            for (int nt = 0; nt < 3; ++nt)
                C[mt][nt] = f32x4{0.f, 0.f, 0.f, 0.f};
        #pragma unroll
        for (int kt = 0; kt < 3; ++kt)
            #pragma unroll
            for (int mt = 0; mt < 3; ++mt)
                #pragma unroll
                for (int nt = 0; nt < 3; ++nt)
                    C[mt][nt] = mfma16(A[mt][kt], Bf[kt][nt], C[mt][nt]);

        float4 w0 = *reinterpret_cast<const float4*>(elds + q * L_ + 4 * g);
        float4 w1 = *reinterpret_cast<const float4*>(elds + q * L_ + 16 + 4 * g);
        float4 w2 = *reinterpret_cast<const float4*>(elds + q * L_ + 32 + 4 * g);

        float rn = 1.f;
        if ((q & 3) == 3) {
            float r = bcastf(C[0][0][0], 0);
            rn = __builtin_amdgcn_rcpf(r);
            lsum += __logf(r);
        }
        float sr[12];
        sr[0] = w0.x * rn; sr[1] = w0.y * rn; sr[2]  = w0.z * rn; sr[3]  = w0.w * rn;
        sr[4] = w1.x * rn; sr[5] = w1.y * rn; sr[6]  = w1.z * rn; sr[7]  = w1.w * rn;
        sr[8] = w2.x * rn; sr[9] = w2.y * rn; sr[10] = w2.z * rn; sr[11] = w2.w * rn;
        #pragma unroll
        for (int mt = 0; mt < 3; ++mt)
            #pragma unroll
            for (int nt = 0; nt < 3; ++nt)
                #pragma unroll
                for (int r = 0; r < 4; ++r)
                    Cst[mt][nt][r] = C[mt][nt][r] * sr[4 * mt + r];
    }

    float* xo = Xout + (size_t)blockIdx.x * 2304;
    #pragma unroll
    for (int mt = 0; mt < 3; ++mt)
        #pragma unroll
        for (int nt = 0; nt < 3; ++nt)
            #pragma unroll
            for (int r = 0; r < 4; ++r)
                xo[(16 * mt + 4 * g + r) * L_ + 16 * nt + l15] = Cst[mt][nt][r];
    if (lane == 0) lsc[blockIdx.x] = lsum;
}

// ---------- Kernel 3: per-batch combine (8 matvecs) + gold sum + ticket reduce ----------
__global__ __launch_bounds__(64) void combine_kernel(const float* __restrict__ Xout,
                                                     const float* __restrict__ lsc,
                                                     const float* __restrict__ gsc,
                                                     const float* __restrict__ trans,
                                                     float* __restrict__ res,
                                                     unsigned* __restrict__ cnt,
                                                     float* __restrict__ out) {
    const int b = blockIdx.x;
    const int j = threadIdx.x;

    float sc = 0.f;
    #pragma unroll
    for (int cc = 0; cc < 8; ++cc) sc += gsc[b * 8 + cc];

    __shared__ float vbuf[64];
    float v = (j == L_ - 2) ? 1.f : 0.f;
    vbuf[j] = v;
    float lsum = 0.f;
    #pragma unroll 1
    for (int c = 0; c < 8; ++c) {
        const float* X = Xout + (size_t)(b * 8 + c) * 2304;
        lsum += lsc[b * 8 + c];
        float acc = 0.f;
        if (j < L_) {
            const float4* vb4 = reinterpret_cast<const float4*>(vbuf);
            const float4* xr = reinterpret_cast<const float4*>(X + j * L_);
            #pragma unroll
            for (int ci = 0; ci < 12; ++ci) {
                float4 xx = xr[ci];
                float4 vv = vb4[ci];
                acc = fmaf(xx.x, vv.x, acc);
                acc = fmaf(xx.y, vv.y, acc);
                acc = fmaf(xx.z, vv.z, acc);
                acc = fmaf(xx.w, vv.w, acc);
            }
        }
        float r = bcastf(acc, 0);              // alpha[0] > 0 always
        float rn = __builtin_amdgcn_rcpf(r);
        lsum += __logf(r);
        v = acc * rn;
        vbuf[j] = (j < L_) ? v : 0.f;
    }

    float term = (j < L_) ? v * __expf(trans[j * L_ + (L_ - 1)]) : 0.f;
    #pragma unroll
    for (int o = 32; o > 0; o >>= 1) term += __shfl_xor(term, o, 64);
    float logz = __logf(term) + lsum;

    if (j == 0) res[b] = logz - sc;
    __threadfence();
    unsigned old = 0;
    if (j == 0) old = atomicAdd(cnt, 1u);
    old = __builtin_amdgcn_readlane(old, 0);
    if (old == B_ - 1) {
        __threadfence();
        volatile const float* vr = res;
        float v2 = vr[j] + vr[64 + j];
        #pragma unroll
        for (int o = 32; o > 0; o >>= 1) v2 += __shfl_xor(v2, o, 64);
        if (j == 0) out[0] = v2;
    }
}

extern "C" void kernel_launch(void* const* d_in, const int* in_sizes, int n_in,
                              void* d_out, int out_size, void* d_ws, size_t ws_size,
                              hipStream_t stream) {
    const float* x      = (const float*)d_in[0];
    const float* W      = (const float*)d_in[1];
    const float* bias   = (const float*)d_in[2];
    const float* trans  = (const float*)d_in[3];
    const int*   tags   = (const int*)d_in[4];
    const int*   seqlen = (const int*)d_in[5];
    float* out = (float*)d_out;

    unsigned short* wpk  = (unsigned short*)d_ws;                          // 98304 B
    unsigned short* etbf = (unsigned short*)((char*)d_ws + 98304);         // 4608 B
    float* Xout          = (float*)((char*)d_ws + 102912);                 // 9437184 B
    float* lsc           = (float*)((char*)d_ws + 9540096);                // 4096 B
    float* gsc           = (float*)((char*)d_ws + 9544192);                // 4096 B
    float* res           = (float*)((char*)d_ws + 9548288);                // 512 B
    unsigned* cnt        = (unsigned*)((char*)d_ws + 9548800);             // 4 B

    hipLaunchKernelGGL(prep_kernel, dim3(192), dim3(256), 0, stream, W, trans, wpk, etbf, cnt);
    hipLaunchKernelGGL(gemmchunk_kernel, dim3(1024), dim3(256), 0, stream,
                       x, wpk, bias, etbf, trans, tags, seqlen, Xout, lsc, gsc);
    hipLaunchKernelGGL(combine_kernel, dim3(B_), dim3(64), 0, stream,
                       Xout, lsc, gsc, trans, res, cnt, out);
}

// Round 20
// 53.406 us; speedup vs baseline: 1.1387x; 1.0402x over previous
//
#include <hip/hip_runtime.h>
#include <hip/hip_bf16.h>

#define B_ 128
#define T_ 256
#define D_ 1024
#define L_ 48
#define SMALL_ (-1000.0f)

typedef float f32x4 __attribute__((ext_vector_type(4)));
typedef short bf16x8 __attribute__((ext_vector_type(8)));
typedef short bf16x4 __attribute__((ext_vector_type(4)));
typedef unsigned u32x4 __attribute__((ext_vector_type(4)));
typedef unsigned u32x2 __attribute__((ext_vector_type(2)));

__device__ __forceinline__ float bcastf(float v, int lane) {
    return __uint_as_float(__builtin_amdgcn_readlane(__float_as_uint(v), lane));
}
__device__ __forceinline__ unsigned cvt_pk_bf16(float lo, float hi) {
    unsigned r;
    asm("v_cvt_pk_bf16_f32 %0, %1, %2" : "=v"(r) : "v"(lo), "v"(hi));
    return r;
}
__device__ __forceinline__ bf16x4 pack4(float a, float b, float c, float d) {
    u32x2 u = {cvt_pk_bf16(a, b), cvt_pk_bf16(c, d)};
    return __builtin_bit_cast(bf16x4, u);
}
__device__ __forceinline__ f32x4 mfma16(bf16x4 a, bf16x4 b, f32x4 c) {
#if __has_builtin(__builtin_amdgcn_mfma_f32_16x16x16bf16_1k)
    return __builtin_amdgcn_mfma_f32_16x16x16bf16_1k(a, b, c, 0, 0, 0);
#else
    asm volatile("v_mfma_f32_16x16x16_bf16 %0, %1, %2, %0" : "+v"(c) : "v"(a), "v"(b));
    return c;
#endif
}
__device__ __forceinline__ unsigned short f2bfu(float f) {
    unsigned u = __float_as_uint(f);
    return (unsigned short)((u + 0x7FFFu + ((u >> 16) & 1u)) >> 16);
}
__device__ __forceinline__ float bf2f(unsigned short u) {
    return __uint_as_float(((unsigned)u) << 16);
}

// ---------- Kernel 1: W -> bf16 fragment-sequential layout, E^T -> bf16, zero ticket ----------
__global__ __launch_bounds__(256) void prep_kernel(const float* __restrict__ W,
                                                   const float* __restrict__ trans,
                                                   unsigned short* __restrict__ wpk,
                                                   unsigned short* __restrict__ etbf,
                                                   unsigned* __restrict__ cnt) {
    int i = blockIdx.x * 256 + threadIdx.x;   // 49152 total
    if (i == 0) *cnt = 0u;
    {
        int e    = i & 7;
        int lane = (i >> 3) & 63;
        int g    = i >> 9;                    // 0..95
        int t    = g % 3;
        int kh   = (g / 3) & 1;
        int r    = g / 6;
        int row  = t * 16 + (lane & 15);
        int col  = r * 64 + kh * 32 + (lane >> 4) * 8 + e;
        wpk[i] = f2bfu(W[row * D_ + col]);
    }
    if (i < L_ * L_) {
        int r = i / L_, k = i - r * L_;       // etbf[r][k] = exp(trans[k][r])
        etbf[i] = f2bfu(__expf(trans[k * L_ + r]));
    }
}

// ---------- Kernel 2: LDS-staged GEMM (depth-2 prefetch, R16-proven) + gold + chunk ----------
// Block i = (b = i>>3, c = i&7) -> rows i*32 .. i*32+31.  NO fences/atomics (R10 lesson).
__global__ __launch_bounds__(256, 4) void gemmchunk_kernel(const float* __restrict__ x,
                                                           const unsigned short* __restrict__ wpk,
                                                           const float* __restrict__ bias,
                                                           const unsigned short* __restrict__ etbf,
                                                           const float* __restrict__ trans,
                                                           const int* __restrict__ tags,
                                                           const int* __restrict__ seq_len,
                                                           unsigned short* __restrict__ Xout,
                                                           float* __restrict__ lsc,
                                                           float* __restrict__ gsc) {
    __shared__ float red[2][64][12];              // 6 KB: K-split reduction
    __shared__ float elds[32 * L_];               // 6 KB: exp(pred) tile
    __shared__ unsigned short xbl[2][32][72];     // 9 KB: bf16 x-tile, dbuf, pad->stride 144B
    const int tid = threadIdx.x;
    const int wv = tid >> 6;
    const int lane = tid & 63;
    const int pair = wv >> 1;
    const int kh = wv & 1;
    const int l16 = lane & 15;
    const int lg  = lane >> 4;
    const int b = blockIdx.x >> 3, c = blockIdx.x & 7;
    const int n = seq_len[b];

    // ---- GEMM phase: staged x (contiguous loads, depth-2 prefetch), fragment-seq W ----
    {
        const int srow = tid >> 4;
        const int scol = (tid & 15) * 4;          // float col base
        const float* xs0 = x + ((size_t)blockIdx.x * 32 + srow) * D_ + scol;
        const float* xs1 = xs0 + 16 * (size_t)D_;
        const unsigned short* wlane = wpk + lane * 8;

        f32x4 acc0 = {0.f,0.f,0.f,0.f}, acc1 = {0.f,0.f,0.f,0.f}, acc2 = {0.f,0.f,0.f,0.f};

        {
            float4 a0 = *reinterpret_cast<const float4*>(xs0);
            float4 a1 = *reinterpret_cast<const float4*>(xs1);
            u32x2 p0 = {cvt_pk_bf16(a0.x, a0.y), cvt_pk_bf16(a0.z, a0.w)};
            u32x2 p1 = {cvt_pk_bf16(a1.x, a1.y), cvt_pk_bf16(a1.z, a1.w)};
            *reinterpret_cast<u32x2*>(&xbl[0][srow][scol]) = p0;
            *reinterpret_cast<u32x2*>(&xbl[0][16 + srow][scol]) = p1;
        }
        float4 s0[2], s1[2];
        s0[1] = *reinterpret_cast<const float4*>(xs0 + 64);
        s1[1] = *reinterpret_cast<const float4*>(xs1 + 64);

        #pragma unroll
        for (int r = 0; r < 16; ++r) {
            if (r + 2 < 16) {
                s0[r & 1] = *reinterpret_cast<const float4*>(xs0 + (r + 2) * 64);
                s1[r & 1] = *reinterpret_cast<const float4*>(xs1 + (r + 2) * 64);
            }
            __syncthreads();                       // buf[r&1] writes visible
            bf16x8 af = *reinterpret_cast<const bf16x8*>(&xbl[r & 1][pair * 16 + l16][kh * 32 + lg * 8]);
            const unsigned short* wp = wlane + ((r * 6 + kh * 3) << 9);
            bf16x8 b0 = *reinterpret_cast<const bf16x8*>(wp);
            bf16x8 b1 = *reinterpret_cast<const bf16x8*>(wp + 512);
            bf16x8 b2 = *reinterpret_cast<const bf16x8*>(wp + 1024);
            acc0 = __builtin_amdgcn_mfma_f32_16x16x32_bf16(af, b0, acc0, 0, 0, 0);
            acc1 = __builtin_amdgcn_mfma_f32_16x16x32_bf16(af, b1, acc1, 0, 0, 0);
            acc2 = __builtin_amdgcn_mfma_f32_16x16x32_bf16(af, b2, acc2, 0, 0, 0);
            if (r + 1 < 16) {
                float4 a0 = s0[(r + 1) & 1];
                float4 a1 = s1[(r + 1) & 1];
                u32x2 p0 = {cvt_pk_bf16(a0.x, a0.y), cvt_pk_bf16(a0.z, a0.w)};
                u32x2 p1 = {cvt_pk_bf16(a1.x, a1.y), cvt_pk_bf16(a1.z, a1.w)};
                *reinterpret_cast<u32x2*>(&xbl[(r + 1) & 1][srow][scol]) = p0;
                *reinterpret_cast<u32x2*>(&xbl[(r + 1) & 1][16 + srow][scol]) = p1;
            }
        }

        if (kh == 1) {
            #pragma unroll
            for (int r = 0; r < 4; ++r) {
                red[pair][lane][r]     = acc0[r];
                red[pair][lane][4 + r] = acc1[r];
                red[pair][lane][8 + r] = acc2[r];
            }
        }
        __syncthreads();
        if (kh == 0) {
            float bi0 = bias[l16], bi1 = bias[16 + l16], bi2 = bias[32 + l16];
            #pragma unroll
            for (int r = 0; r < 4; ++r) {
                float v0 = acc0[r] + red[pair][lane][r]     + bi0;
                float v1 = acc1[r] + red[pair][lane][4 + r] + bi1;
                float v2 = acc2[r] + red[pair][lane][8 + r] + bi2;
                int lrow = pair * 16 + lg * 4 + r;
                elds[lrow * L_ + l16]      = __expf(v0);
                elds[lrow * L_ + 16 + l16] = __expf(v1);
                elds[lrow * L_ + 32 + l16] = (32 + l16 >= L_ - 2) ? 0.f : __expf(v2);
            }
        }
    }
    __syncthreads();                  // elds complete
    if (wv >= 2) return;              // R8 retirement profile

    if (wv == 1) {
        // ---- gold-path partial for rows [c*32, c*32+32), pred = log(elds) ----
        const int* tg = tags + b * T_;
        float s = 0.f;
        int t = c * 32 + lane;        // lanes 0..31 active
        if (lane < 32 && t < n) {
            int tag = tg[t];
            int pt = (t == 0) ? (L_ - 2) : tg[t - 1];
            s = __logf(elds[lane * L_ + tag]) + trans[pt * L_ + tag];
            if (t == n - 1) s += trans[tag * L_ + (L_ - 1)];
        }
        #pragma unroll
        for (int o = 32; o > 0; o >>= 1) s += __shfl_xor(s, o, 64);
        if (lane == 0) gsc[blockIdx.x] = s;
        return;
    }

    // ---- chunk product (R7/R8-proven), wave 0 only ----
    int nsteps = n - c * 32;
    nsteps = nsteps < 0 ? 0 : (nsteps > 32 ? 32 : nsteps);

    const int l15 = lane & 15, g = lane >> 4;
    bf16x4 A[3][3];
    #pragma unroll
    for (int mt = 0; mt < 3; ++mt)
        #pragma unroll
        for (int kt = 0; kt < 3; ++kt)
            A[mt][kt] = *reinterpret_cast<const bf16x4*>(etbf + (16 * mt + l15) * L_ + 16 * kt + 4 * g);

    f32x4 Cst[3][3];
    #pragma unroll
    for (int mt = 0; mt < 3; ++mt)
        #pragma unroll
        for (int nt = 0; nt < 3; ++nt)
            #pragma unroll
            for (int r = 0; r < 4; ++r)
                Cst[mt][nt][r] = (mt == nt && 4 * g + r == l15) ? 1.f : 0.f;

    float lsum = 0.f;
    for (int q = 0; q < nsteps; ++q) {
        bf16x4 Bf[3][3];
        #pragma unroll
        for (int kt = 0; kt < 3; ++kt)
            #pragma unroll
            for (int nt = 0; nt < 3; ++nt)
                Bf[kt][nt] = pack4(Cst[kt][nt][0], Cst[kt][nt][1], Cst[kt][nt][2], Cst[kt][nt][3]);

        f32x4 C[3][3];
        #pragma unroll
        for (int mt = 0; mt < 3; ++mt)
            #pragma unroll
            for (int nt = 0; nt < 3; ++nt)
                C[mt][nt] = f32x4{0.f, 0.f, 0.f, 0.f};
        #pragma unroll
        for (int kt = 0; kt < 3; ++kt)
            #pragma unroll
            for (int mt = 0; mt < 3; ++mt)
                #pragma unroll
                for (int nt = 0; nt < 3; ++nt)
                    C[mt][nt] = mfma16(A[mt][kt], Bf[kt][nt], C[mt][nt]);

        float4 w0 = *reinterpret_cast<const float4*>(elds + q * L_ + 4 * g);
        float4 w1 = *reinterpret_cast<const float4*>(elds + q * L_ + 16 + 4 * g);
        float4 w2 = *reinterpret_cast<const float4*>(elds + q * L_ + 32 + 4 * g);

        float rn = 1.f;
        if ((q & 3) == 3) {
            float r = bcastf(C[0][0][0], 0);
            rn = __builtin_amdgcn_rcpf(r);
            lsum += __logf(r);
        }
        float sr[12];
        sr[0] = w0.x * rn; sr[1] = w0.y * rn; sr[2]  = w0.z * rn; sr[3]  = w0.w * rn;
        sr[4] = w1.x * rn; sr[5] = w1.y * rn; sr[6]  = w1.z * rn; sr[7]  = w1.w * rn;
        sr[8] = w2.x * rn; sr[9] = w2.y * rn; sr[10] = w2.z * rn; sr[11] = w2.w * rn;
        #pragma unroll
        for (int mt = 0; mt < 3; ++mt)
            #pragma unroll
            for (int nt = 0; nt < 3; ++nt)
                #pragma unroll
                for (int r = 0; r < 4; ++r)
                    Cst[mt][nt][r] = C[mt][nt][r] * sr[4 * mt + r];
    }

    // store X as bf16 (RNE) and log-scale
    unsigned short* xo = Xout + (size_t)blockIdx.x * 2304;
    #pragma unroll
    for (int mt = 0; mt < 3; ++mt)
        #pragma unroll
        for (int nt = 0; nt < 3; ++nt)
            #pragma unroll
            for (int r = 0; r < 4; ++r)
                xo[(16 * mt + 4 * g + r) * L_ + 16 * nt + l15] = f2bfu(Cst[mt][nt][r]);
    if (lane == 0) lsc[blockIdx.x] = lsum;
}

// ---------- Kernel 3: per-batch combine (8 bf16 matvecs) + gold sum + ticket reduce ----------
__global__ __launch_bounds__(64) void combine_kernel(const unsigned short* __restrict__ Xout,
                                                     const float* __restrict__ lsc,
                                                     const float* __restrict__ gsc,
                                                     const float* __restrict__ trans,
                                                     float* __restrict__ res,
                                                     unsigned* __restrict__ cnt,
                                                     float* __restrict__ out) {
    const int b = blockIdx.x;
    const int j = threadIdx.x;

    float sc = 0.f;
    #pragma unroll
    for (int cc = 0; cc < 8; ++cc) sc += gsc[b * 8 + cc];

    __shared__ float vbuf[64];
    float v = (j == L_ - 2) ? 1.f : 0.f;
    vbuf[j] = v;
    float lsum = 0.f;
    #pragma unroll 1
    for (int c = 0; c < 8; ++c) {
        const unsigned short* X = Xout + (size_t)(b * 8 + c) * 2304;
        lsum += lsc[b * 8 + c];
        float acc = 0.f;
        if (j < L_) {
            const float4* vb4 = reinterpret_cast<const float4*>(vbuf);
            const unsigned short* xr = X + j * L_;
            #pragma unroll
            for (int blk = 0; blk < 6; ++blk) {
                bf16x8 x8 = *reinterpret_cast<const bf16x8*>(xr + blk * 8);
                float4 va = vb4[2 * blk];
                float4 vb = vb4[2 * blk + 1];
                acc = fmaf(bf2f((unsigned short)x8[0]), va.x, acc);
                acc = fmaf(bf2f((unsigned short)x8[1]), va.y, acc);
                acc = fmaf(bf2f((unsigned short)x8[2]), va.z, acc);
                acc = fmaf(bf2f((unsigned short)x8[3]), va.w, acc);
                acc = fmaf(bf2f((unsigned short)x8[4]), vb.x, acc);
                acc = fmaf(bf2f((unsigned short)x8[5]), vb.y, acc);
                acc = fmaf(bf2f((unsigned short)x8[6]), vb.z, acc);
                acc = fmaf(bf2f((unsigned short)x8[7]), vb.w, acc);
            }
        }
        float r = bcastf(acc, 0);              // alpha[0] > 0 always
        float rn = __builtin_amdgcn_rcpf(r);
        lsum += __logf(r);
        v = acc * rn;
        vbuf[j] = (j < L_) ? v : 0.f;
    }

    float term = (j < L_) ? v * __expf(trans[j * L_ + (L_ - 1)]) : 0.f;
    #pragma unroll
    for (int o = 32; o > 0; o >>= 1) term += __shfl_xor(term, o, 64);
    float logz = __logf(term) + lsum;

    if (j == 0) res[b] = logz - sc;
    __threadfence();
    unsigned old = 0;
    if (j == 0) old = atomicAdd(cnt, 1u);
    old = __builtin_amdgcn_readlane(old, 0);
    if (old == B_ - 1) {
        __threadfence();
        volatile const float* vr = res;
        float v2 = vr[j] + vr[64 + j];
        #pragma unroll
        for (int o = 32; o > 0; o >>= 1) v2 += __shfl_xor(v2, o, 64);
        if (j == 0) out[0] = v2;
    }
}

extern "C" void kernel_launch(void* const* d_in, const int* in_sizes, int n_in,
                              void* d_out, int out_size, void* d_ws, size_t ws_size,
                              hipStream_t stream) {
    const float* x      = (const float*)d_in[0];
    const float* W      = (const float*)d_in[1];
    const float* bias   = (const float*)d_in[2];
    const float* trans  = (const float*)d_in[3];
    const int*   tags   = (const int*)d_in[4];
    const int*   seqlen = (const int*)d_in[5];
    float* out = (float*)d_out;

    unsigned short* wpk  = (unsigned short*)d_ws;                          // 98304 B
    unsigned short* etbf = (unsigned short*)((char*)d_ws + 98304);         // 4608 B
    unsigned short* Xout = (unsigned short*)((char*)d_ws + 102912);        // 4718592 B (1024 x 2304 bf16)
    float* lsc           = (float*)((char*)d_ws + 4821504);                // 4096 B
    float* gsc           = (float*)((char*)d_ws + 4825600);                // 4096 B
    float* res           = (float*)((char*)d_ws + 4829696);                // 512 B
    unsigned* cnt        = (unsigned*)((char*)d_ws + 4830208);             // 4 B

    hipLaunchKernelGGL(prep_kernel, dim3(192), dim3(256), 0, stream, W, trans, wpk, etbf, cnt);
    hipLaunchKernelGGL(gemmchunk_kernel, dim3(1024), dim3(256), 0, stream,
                       x, wpk, bias, etbf, trans, tags, seqlen, Xout, lsc, gsc);
    hipLaunchKernelGGL(combine_kernel, dim3(B_), dim3(64), 0, stream,
                       Xout, lsc, gsc, trans, res, cnt, out);
}